// Round 10
// baseline (262.999 us; speedup 1.0000x reference)
//
#include <hip/hip_runtime.h>
#include <hip/hip_bf16.h>

typedef __attribute__((ext_vector_type(8))) __bf16 bf16x8;
typedef __attribute__((ext_vector_type(4))) short short4v;
typedef __attribute__((ext_vector_type(4))) float f32x4;
typedef __attribute__((ext_vector_type(16))) float f32x16;
typedef __attribute__((ext_vector_type(4))) unsigned int uint4v;
typedef __attribute__((ext_vector_type(2))) unsigned int uint2v;

#define S_LEN 2048
#define DIM_  1024
#define HDIM  64
// SCALE * log2(e), folded into Q at projection time
#define SCALE2 0.045084441f

#define EXP2F(x) __builtin_amdgcn_exp2f(x)

// 16B-granularity XOR swizzle for [R][64] bf16 LDS tiles (rows = 128 B).
#define ATTN_SWZ(row, col8) (((row) * 64) + (((col8) ^ ((row) & 7)) << 3))

__device__ __forceinline__ void async_copy16(const void* gp, void* lp) {
  __builtin_amdgcn_global_load_lds(
      (const __attribute__((address_space(1))) unsigned int*)gp,
      (__attribute__((address_space(3))) unsigned int*)lp, 16, 0, 0);
}

__device__ __forceinline__ unsigned f2bf_u(float f) {
  unsigned u = __builtin_bit_cast(unsigned, f);
  return (u + 0x7FFFu + ((u >> 16) & 1u)) >> 16;
}
__device__ __forceinline__ unsigned pack2(float a, float b) {
  return f2bf_u(a) | (f2bf_u(b) << 16);
}
// single-instruction packed f32x2 -> bf16x2 (v_cvt_pk_bf16_f32), a in low half
__device__ __forceinline__ unsigned cvtpk(float a, float b) {
  float2 f; f.x = a; f.y = b;
  __hip_bfloat162 h = __float22bfloat162_rn(f);
  unsigned u;
  __builtin_memcpy(&u, &h, 4);
  return u;
}

// ---------------- input f32 -> bf16 conversion + mask ballot (fused) ----------------
__global__ __launch_bounds__(256) void cvt_kernel(
    const float* __restrict__ s0, const float* __restrict__ s1, const float* __restrict__ s2,
    const float* __restrict__ s3, const float* __restrict__ s4, const float* __restrict__ s5,
    const float* __restrict__ s6,
    __hip_bfloat16* __restrict__ d0, __hip_bfloat16* __restrict__ d1, __hip_bfloat16* __restrict__ d2,
    __hip_bfloat16* __restrict__ d3, __hip_bfloat16* __restrict__ d4, __hip_bfloat16* __restrict__ d5,
    __hip_bfloat16* __restrict__ d6,
    const int* __restrict__ mask, unsigned long long* __restrict__ bits)
{
  if (blockIdx.y == 7) {
    // mask int32 -> 64-bit words via ballot; 16 words per wave
    int wave = threadIdx.x >> 6, lane = threadIdx.x & 63;
    int gw = blockIdx.x * 4 + wave;           // 0..8191
#pragma unroll
    for (int it = 0; it < 16; ++it) {
      int w = gw * 16 + it;                   // 0..131071
      int m = mask[(size_t)w * 64 + lane];
      unsigned long long bal = __ballot(m != 0);
      if (lane == 0) bits[w] = bal;
    }
    return;
  }
  const float* srcs[7] = {s0, s1, s2, s3, s4, s5, s6};
  __hip_bfloat16* dsts[7] = {d0, d1, d2, d3, d4, d5, d6};
  const int sizes[7] = {4194304, 4194304, 4194304, 1048576, 1048576, 1048576, 1048576};
  int rg = blockIdx.y;
  int base = (blockIdx.x * 256 + threadIdx.x) * 8;
  if (base >= sizes[rg]) return;
  const float* s = srcs[rg] + base;
  f32x4 a = *(const f32x4*)s;
  f32x4 b = *(const f32x4*)(s + 4);
  uint4v o;
  o.x = pack2(a[0], a[1]); o.y = pack2(a[2], a[3]);
  o.z = pack2(b[0], b[1]); o.w = pack2(b[2], b[3]);
  *(uint4v*)(dsts[rg] + base) = o;
}

// XCD-aware L2 swizzle: blocks sharing one W-panel (same n0) co-locate on one XCD.
__device__ __forceinline__ void swz(int r, int& m0, int& n0) {
  int c  = ((r & 7) << 2) | (r >> 6);  // combo 0..31
  int xl = (r >> 3) & 7;
  m0 = ((c >> 3) * 8 + xl) * 128;
  n0 = (c & 7) * 128;
}

// ---------------- QKV projection (bf16, double-buffered async staging) ----------------
__global__ __launch_bounds__(256) void qkv_gemm_kernel(
    const __hip_bfloat16* __restrict__ xq, const __hip_bfloat16* __restrict__ xk,
    const __hip_bfloat16* __restrict__ xv,
    const __hip_bfloat16* __restrict__ Wq, const float* __restrict__ bq,
    const __hip_bfloat16* __restrict__ Wk, const float* __restrict__ bk,
    const __hip_bfloat16* __restrict__ Wv, const float* __restrict__ bv,
    __hip_bfloat16* __restrict__ Q, __hip_bfloat16* __restrict__ Kk,
    __hip_bfloat16* __restrict__ VT)
{
  const __hip_bfloat16 *X, *W; const float* bias;
  if (blockIdx.z == 0)      { X = xq; W = Wq; bias = bq; }
  else if (blockIdx.z == 1) { X = xk; W = Wk; bias = bk; }
  else                      { X = xv; W = Wv; bias = bv; }

  constexpr int K = 1024, N = 1024;
  __shared__ alignas(16) __hip_bfloat16 SM[4][128 * 32];
  const int tid  = threadIdx.x;
  const int lane = tid & 63;
  const int wave = tid >> 6;
  const int t    = lane & 15;
  const int quad = lane >> 4;
  const int wm   = wave >> 1;
  const int wn   = wave & 1;
  int m0, n0;
  swz(blockIdx.x, m0, n0);

  f32x4 acc[4][4] = {};

  const int c0 = tid, c1 = 256 + tid;
  const int r0 = c0 >> 2, o0 = (c0 & 3) * 8;
  const int r1 = c1 >> 2, o1 = (c1 & 3) * 8;
  const __hip_bfloat16* xp0 = &X[(size_t)(m0 + r0) * K + o0];
  const __hip_bfloat16* xp1 = &X[(size_t)(m0 + r1) * K + o1];
  const __hip_bfloat16* wp0 = &W[(size_t)(n0 + r0) * K + o0];
  const __hip_bfloat16* wp1 = &W[(size_t)(n0 + r1) * K + o1];

  async_copy16(xp0, &SM[0][c0 * 8]);
  async_copy16(xp1, &SM[0][c1 * 8]);
  async_copy16(wp0, &SM[2][c0 * 8]);
  async_copy16(wp1, &SM[2][c1 * 8]);

  int buf = 0;
  for (int k0 = 0; k0 < K; k0 += 32) {
    __syncthreads();
    if (k0 + 32 < K) {
      int nb = buf ^ 1;
      int kn = k0 + 32;
      async_copy16(xp0 + kn, &SM[nb][c0 * 8]);
      async_copy16(xp1 + kn, &SM[nb][c1 * 8]);
      async_copy16(wp0 + kn, &SM[2 + nb][c0 * 8]);
      async_copy16(wp1 + kn, &SM[2 + nb][c1 * 8]);
    }
    bf16x8 a[4], b[4];
#pragma unroll
    for (int i = 0; i < 4; ++i)
      a[i] = *(const bf16x8*)&SM[buf][(wm * 64 + i * 16 + t) * 32 + quad * 8];
#pragma unroll
    for (int j = 0; j < 4; ++j)
      b[j] = *(const bf16x8*)&SM[2 + buf][(wn * 64 + j * 16 + t) * 32 + quad * 8];
#pragma unroll
    for (int i = 0; i < 4; ++i)
#pragma unroll
      for (int j = 0; j < 4; ++j)
        acc[i][j] = __builtin_amdgcn_mfma_f32_16x16x32_bf16(a[i], b[j], acc[i][j], 0, 0, 0);
    buf ^= 1;
  }

  float bj[4];
#pragma unroll
  for (int j = 0; j < 4; ++j)
    bj[j] = bias[n0 + wn * 64 + j * 16 + t];

  __syncthreads();
  __hip_bfloat16* SMf = &SM[0][0];

  if (blockIdx.z == 2) {
#pragma unroll
    for (int i = 0; i < 4; ++i) {
      int mlb = wm * 8 + i * 2 + (quad >> 1);
#pragma unroll
      for (int j = 0; j < 4; ++j) {
        int nl = wn * 64 + j * 16 + t;
        int blk = (mlb & 8) | ((mlb & 7) ^ (nl & 7));
        uint2v pk;
        pk.x = pack2(acc[i][j][0] + bj[j], acc[i][j][1] + bj[j]);
        pk.y = pack2(acc[i][j][2] + bj[j], acc[i][j][3] + bj[j]);
        *(uint2v*)&SMf[nl * 128 + blk * 8 + (quad & 1) * 4] = pk;
      }
    }
    __syncthreads();
    const int bb = m0 >> 11, kv0 = m0 & 2047;
#pragma unroll
    for (int pass = 0; pass < 8; ++pass) {
      int nl = pass * 16 + (tid >> 4);
      int lb = tid & 15;
      int blk = (lb & 8) | ((lb & 7) ^ (nl & 7));
      uint4 x = *(const uint4*)&SMf[nl * 128 + blk * 8];
      *(uint4*)&VT[(size_t)(bb * 1024 + n0 + nl) * 2048 + kv0 + lb * 8] = x;
    }
  } else {
    const bool isq = (blockIdx.z == 0);
    __hip_bfloat16* Out = isq ? Q : Kk;
    const float sc = isq ? SCALE2 : 1.0f;
#pragma unroll
    for (int i = 0; i < 4; ++i)
#pragma unroll
      for (int j = 0; j < 4; ++j) {
        int nlb = wn * 8 + j * 2 + (t >> 3);
        int nin = t & 7;
#pragma unroll
        for (int r = 0; r < 4; ++r) {
          int ml = wm * 64 + i * 16 + quad * 4 + r;
          int blk = (nlb & 8) | ((nlb & 7) ^ (ml & 7));
          SMf[ml * 128 + blk * 8 + nin] =
              __float2bfloat16((acc[i][j][r] + bj[j]) * sc);
        }
      }
    __syncthreads();
#pragma unroll
    for (int pass = 0; pass < 8; ++pass) {
      int ml = pass * 16 + (tid >> 4);
      int lb = tid & 15;
      int blk = (lb & 8) | ((lb & 7) ^ (ml & 7));
      uint4 x = *(const uint4*)&SMf[ml * 128 + blk * 8];
      *(uint4*)&Out[(size_t)(m0 + ml) * N + n0 + lb * 8] = x;
    }
  }
}

// ---------------- Output projection (double-buffered) ----------------
__global__ __launch_bounds__(256) void proj_gemm_kernel(
    const __hip_bfloat16* __restrict__ X, const __hip_bfloat16* __restrict__ W,
    const float* __restrict__ bias, float* __restrict__ Out)
{
  constexpr int K = 1024, N = 1024;
  __shared__ alignas(16) __hip_bfloat16 As[2][128 * 32];
  __shared__ alignas(16) __hip_bfloat16 Bs[2][128 * 32];
  const int tid  = threadIdx.x;
  const int lane = tid & 63;
  const int wave = tid >> 6;
  const int t    = lane & 15;
  const int quad = lane >> 4;
  const int wm   = wave >> 1;
  const int wn   = wave & 1;
  int m0, n0;
  swz(blockIdx.x, m0, n0);

  f32x4 acc[4][4] = {};

  const int c0 = tid, c1 = 256 + tid;
  const int r0 = c0 >> 2, o0 = (c0 & 3) * 8;
  const int r1 = c1 >> 2, o1 = (c1 & 3) * 8;
  const __hip_bfloat16* xp0 = &X[(size_t)(m0 + r0) * K + o0];
  const __hip_bfloat16* xp1 = &X[(size_t)(m0 + r1) * K + o1];
  const __hip_bfloat16* wp0 = &W[(size_t)(n0 + r0) * K + o0];
  const __hip_bfloat16* wp1 = &W[(size_t)(n0 + r1) * K + o1];

  async_copy16(xp0, &As[0][c0 * 8]);
  async_copy16(xp1, &As[0][c1 * 8]);
  async_copy16(wp0, &Bs[0][c0 * 8]);
  async_copy16(wp1, &Bs[0][c1 * 8]);

  int buf = 0;
  for (int k0 = 0; k0 < K; k0 += 32) {
    __syncthreads();
    if (k0 + 32 < K) {
      int nb = buf ^ 1;
      int kn = k0 + 32;
      async_copy16(xp0 + kn, &As[nb][c0 * 8]);
      async_copy16(xp1 + kn, &As[nb][c1 * 8]);
      async_copy16(wp0 + kn, &Bs[nb][c0 * 8]);
      async_copy16(wp1 + kn, &Bs[nb][c1 * 8]);
    }
    bf16x8 a[4], b[4];
#pragma unroll
    for (int i = 0; i < 4; ++i)
      a[i] = *(const bf16x8*)&As[buf][(wm * 64 + i * 16 + t) * 32 + quad * 8];
#pragma unroll
    for (int j = 0; j < 4; ++j)
      b[j] = *(const bf16x8*)&Bs[buf][(wn * 64 + j * 16 + t) * 32 + quad * 8];
#pragma unroll
    for (int i = 0; i < 4; ++i)
#pragma unroll
      for (int j = 0; j < 4; ++j)
        acc[i][j] = __builtin_amdgcn_mfma_f32_16x16x32_bf16(a[i], b[j], acc[i][j], 0, 0, 0);
    buf ^= 1;
  }

  float bj[4];
#pragma unroll
  for (int j = 0; j < 4; ++j)
    bj[j] = bias[n0 + wn * 64 + j * 16 + t];
#pragma unroll
  for (int i = 0; i < 4; ++i)
#pragma unroll
    for (int j = 0; j < 4; ++j)
#pragma unroll
      for (int r = 0; r < 4; ++r) {
        int m = m0 + wm * 64 + i * 16 + quad * 4 + r;
        int n = n0 + wn * 64 + j * 16 + t;
        Out[(size_t)m * N + n] = acc[i][j][r] + bj[j];
      }
}

// ---------------- Flash attention (R15: 32x32x16 MFMA, 2-wave blocks) ----------------
// Per wave: 32 q rows. QK^T: St[32kv][32q] via mfma_32x32x16(K,Q), C-layout
// col=lane&31=q, row=(reg&3)+8*(reg>>2)+4*(lane>>5)=kv (m74/m101-verified).
// PV B-frag needs kv k=8*(lane>>5)+e -> cross-half exchange via shfl_xor(32).
// 16 MFMA + 16 ds_read_b128 per 32q per 64kv tile (was 48+48).
__global__ __launch_bounds__(128) void attn_kernel(
    const __hip_bfloat16* __restrict__ Qb,
    const __hip_bfloat16* __restrict__ Kb,
    const __hip_bfloat16* __restrict__ VT,
    const unsigned long long* __restrict__ mbits,
    __hip_bfloat16* __restrict__ Ob)
{
  const int bid = blockIdx.x;
  // XCD-aware remap (same as R11): bid%8 = XCD
  const int qt = (bid >> 3) & 31;
  const int g  = ((bid & 7) << 2) | (bid >> 8);
  const int h  = g & 15;
  const int b  = g >> 4;
  const int qb = qt * 64;

  __shared__ alignas(16) __hip_bfloat16 Qs[64 * 64];
  __shared__ alignas(16) __hip_bfloat16 Ks[2][64 * 64];
  __shared__ alignas(16) __hip_bfloat16 Vt[2][64 * 64];   // Vt[dv][kv]

  const int tid  = threadIdx.x;      // 0..127
  const int lane = tid & 63;
  const int wave = tid >> 6;         // 0..1
  const int qc   = lane & 31;        // q column
  const int hh   = lane >> 5;        // lane half

  // staging: 4 chunks/thread/matrix; rows srow+16i keep (row&7)=srow&7 so one
  // pre-swizzled source column works for all chunks and tiles.
  const int srow = tid >> 3;                            // 0..15
  const int scol = ((tid & 7) ^ (srow & 7)) << 3;       // elems
  const __hip_bfloat16* kpp = &Kb[((size_t)(b * S_LEN + srow)) * DIM_ + h * HDIM + scol];
  const size_t vtbase = (size_t)((b * 16 + h) * 64) * 2048;
  const __hip_bfloat16* vpp = &VT[vtbase + (size_t)srow * 2048 + scol];

  // prologue: stage K/V tile 0 into buf 0
#pragma unroll
  for (int i = 0; i < 4; ++i) {
    async_copy16(kpp + (size_t)i * 16 * DIM_, &Ks[0][(i * 128 + tid) * 8]);
    async_copy16(vpp + (size_t)i * 16 * 2048, &Vt[0][(i * 128 + tid) * 8]);
  }

  // stage Q (swizzled, sync): 64 rows
#pragma unroll
  for (int i = 0; i < 4; ++i) {
    int c = i * 128 + tid;
    int row = c >> 3, c8 = c & 7;
    uint4 raw = *(const uint4*)&Qb[((size_t)(b * S_LEN + qb + row)) * DIM_ + h * HDIM + c8 * 8];
    *(uint4*)&Qs[ATTN_SWZ(row, c8)] = raw;
  }
  __syncthreads();   // Q ready, tile0 staged

  // Q B-frags: col=q=qc, k(d) = j*16 + hh*8 + e
  bf16x8 qf[4];
#pragma unroll
  for (int j = 0; j < 4; ++j)
    qf[j] = *(const bf16x8*)&Qs[ATTN_SWZ(wave * 32 + qc, 2 * j + hh)];

  f32x4 lp4 = {0.f, 0.f, 0.f, 0.f};
  f32x16 oacc[2] = {};   // O^T[dv = 32G + 8m + 4hh + ri][q = qc]

  const size_t mbase = ((size_t)b * S_LEN + qb + wave * 32 + qc) * 32;

// one kv-tile body; BUF compile-time (0/1)
#define ATTN_TILE(kvt, BUF)                                                   \
  {                                                                           \
    unsigned long long mw = mbits[mbase + (kvt)];                             \
    if ((kvt) > 0) __syncthreads();                                           \
    if ((kvt) + 1 < 32) {                                                     \
      size_t ko = (size_t)((kvt) + 1) * 64 * DIM_;                            \
      int    vo = ((kvt) + 1) * 64;                                           \
      _Pragma("unroll")                                                       \
      for (int i = 0; i < 4; ++i) {                                           \
        async_copy16(kpp + ko + (size_t)i * 16 * DIM_,                        \
                     &Ks[(BUF) ^ 1][(i * 128 + tid) * 8]);                    \
        async_copy16(vpp + vo + (size_t)i * 16 * 2048,                        \
                     &Vt[(BUF) ^ 1][(i * 128 + tid) * 8]);                    \
      }                                                                       \
    }                                                                         \
    __builtin_amdgcn_s_setprio(1);                                            \
    _Pragma("unroll")                                                         \
    for (int T = 0; T < 2; ++T) {                                             \
      f32x16 z = {};                                                          \
      _Pragma("unroll")                                                       \
      for (int j = 0; j < 4; ++j) {                                           \
        bf16x8 kf = *(const bf16x8*)&Ks[BUF][ATTN_SWZ(T * 32 + qc, 2 * j + hh)];\
        z = __builtin_amdgcn_mfma_f32_32x32x16_bf16(kf, qf[j], z, 0, 0, 0);   \
      }                                                                       \
      unsigned u = (unsigned)(mw >> (T * 32 + 4 * hh));                       \
      unsigned Dm[4][2];                                                      \
      _Pragma("unroll")                                                       \
      for (int m = 0; m < 4; ++m) {                                           \
        unsigned nib = (u >> (8 * m)) & 0xFu;                                 \
        float e0 = EXP2F((nib & 1u) ? -1e20f : z[4 * m + 0]);                 \
        float e1 = EXP2F((nib & 2u) ? -1e20f : z[4 * m + 1]);                 \
        float e2 = EXP2F((nib & 4u) ? -1e20f : z[4 * m + 2]);                 \
        float e3 = EXP2F((nib & 8u) ? -1e20f : z[4 * m + 3]);                 \
        lp4[0] += e0; lp4[1] += e1; lp4[2] += e2; lp4[3] += e3;               \
        Dm[m][0] = cvtpk(e0, e1);                                             \
        Dm[m][1] = cvtpk(e2, e3);                                             \
      }                                                                       \
      _Pragma("unroll")                                                       \
      for (int ks = 0; ks < 2; ++ks) {                                        \
        unsigned A0 = Dm[2 * ks][0],     A1 = Dm[2 * ks][1];                  \
        unsigned B0 = Dm[2 * ks + 1][0], B1 = Dm[2 * ks + 1][1];              \
        unsigned pA0 = __shfl_xor(A0, 32, 64);                                \
        unsigned pA1 = __shfl_xor(A1, 32, 64);                                \
        unsigned pB0 = __shfl_xor(B0, 32, 64);                                \
        unsigned pB1 = __shfl_xor(B1, 32, 64);                                \
        uint4v wv;                                                            \
        wv.x = hh ? pB0 : A0;                                                 \
        wv.y = hh ? pB1 : A1;                                                 \
        wv.z = hh ? B0 : pA0;                                                 \
        wv.w = hh ? B1 : pA1;                                                 \
        bf16x8 pfrag = __builtin_bit_cast(bf16x8, wv);                        \
        _Pragma("unroll")                                                     \
        for (int G = 0; G < 2; ++G) {                                         \
          bf16x8 vfrag = *(const bf16x8*)&Vt[BUF][                            \
              ATTN_SWZ(G * 32 + qc, 4 * T + 2 * ks + hh)];                    \
          oacc[G] = __builtin_amdgcn_mfma_f32_32x32x16_bf16(vfrag, pfrag,     \
                                                            oacc[G], 0, 0, 0);\
        }                                                                     \
      }                                                                       \
    }                                                                         \
    __builtin_amdgcn_s_setprio(0);                                            \
  }

  ATTN_TILE(0, 0)
  for (int kvt = 1; kvt < 31; kvt += 2) {
    ATTN_TILE(kvt, 1)
    ATTN_TILE(kvt + 1, 0)
  }
  ATTN_TILE(31, 1)
#undef ATTN_TILE

  // denominator: lane holds 32 of each tile's 64 kv; partner half has the rest
  float lp = (lp4[0] + lp4[1]) + (lp4[2] + lp4[3]);
  lp += __shfl_xor(lp, 32, 64);
  float rl = 1.0f / lp;

  // O^T -> O via Qs (swizzled), coalesced store
  __hip_bfloat16* Ts = Qs;
  __syncthreads();
  {
    int row = wave * 32 + qc;
#pragma unroll
    for (int G = 0; G < 2; ++G)
#pragma unroll
      for (int m = 0; m < 4; ++m) {
        uint2v pk;
        pk.x = cvtpk(oacc[G][4 * m + 0] * rl, oacc[G][4 * m + 1] * rl);
        pk.y = cvtpk(oacc[G][4 * m + 2] * rl, oacc[G][4 * m + 3] * rl);
        *(uint2v*)&Ts[row * 64 + (((4 * G + m) ^ (row & 7)) << 3) + 4 * hh] = pk;
      }
  }
  __syncthreads();
  {
#pragma unroll
    for (int i = 0; i < 2; ++i) {
      int tt = i * 128 + tid;
      int row = tt >> 2;             // q local 0..63
      int half = (tt >> 1) & 1;
      int bb = tt & 1;
      __hip_bfloat16* dst = &Ob[((size_t)(b * S_LEN + qb + row)) * DIM_ + h * HDIM];
#pragma unroll
      for (int s = 0; s < 2; ++s) {
        int blk = half * 4 + bb * 2 + s;
        uint4 x = *(const uint4*)&Ts[row * 64 + ((blk ^ (row & 7)) << 3)];
        *(uint4*)(dst + blk * 8) = x;
      }
    }
  }
}

extern "C" void kernel_launch(void* const* d_in, const int* in_sizes, int n_in,
                              void* d_out, int out_size, void* d_ws, size_t ws_size,
                              hipStream_t stream) {
  const float* q  = (const float*)d_in[0];
  const float* k  = (const float*)d_in[1];
  const float* v  = (const float*)d_in[2];
  const int*   mk = (const int*)d_in[3];
  const float* Wq = (const float*)d_in[4];
  const float* bq = (const float*)d_in[5];
  const float* Wk = (const float*)d_in[6];
  const float* bk = (const float*)d_in[7];
  const float* Wv = (const float*)d_in[8];
  const float* bv = (const float*)d_in[9];
  const float* Wo = (const float*)d_in[10];
  const float* bo = (const float*)d_in[11];
  float* out = (float*)d_out;

  char* ws = (char*)d_ws;
  const size_t MB = 1024 * 1024;
  __hip_bfloat16* Qb  = (__hip_bfloat16*)(ws);
  __hip_bfloat16* Kb  = (__hip_bfloat16*)(ws + 8  * MB);
  __hip_bfloat16* VTb = (__hip_bfloat16*)(ws + 16 * MB);
  __hip_bfloat16* Ob  = (__hip_bfloat16*)(ws + 24 * MB);
  __hip_bfloat16* xqb = (__hip_bfloat16*)(ws + 32 * MB);
  __hip_bfloat16* xkb = (__hip_bfloat16*)(ws + 40 * MB);
  __hip_bfloat16* xvb = (__hip_bfloat16*)(ws + 48 * MB);
  __hip_bfloat16* Wqb = (__hip_bfloat16*)(ws + 56 * MB);
  __hip_bfloat16* Wkb = (__hip_bfloat16*)(ws + 58 * MB);
  __hip_bfloat16* Wvb = (__hip_bfloat16*)(ws + 60 * MB);
  __hip_bfloat16* Wob = (__hip_bfloat16*)(ws + 62 * MB);
  unsigned long long* mbits = (unsigned long long*)(ws + 64 * MB);

  cvt_kernel<<<dim3(2048, 8), 256, 0, stream>>>(q, k, v, Wq, Wk, Wv, Wo,
                                                xqb, xkb, xvb, Wqb, Wkb, Wvb, Wob,
                                                mk, mbits);
  qkv_gemm_kernel<<<dim3(256, 1, 3), 256, 0, stream>>>(xqb, xkb, xvb,
                                                       Wqb, bq, Wkb, bk, Wvb, bv,
                                                       Qb, Kb, VTb);
  attn_kernel<<<dim3(1024), 128, 0, stream>>>(Qb, Kb, VTb, mbits, Ob);
  proj_gemm_kernel<<<dim3(256), 256, 0, stream>>>(Ob, Wob, bo, out);
}